// Round 2
// baseline (334.187 us; speedup 1.0000x reference)
//
#include <hip/hip_runtime.h>
#include <hip/hip_bf16.h>

// Encoder_multi: zero-state single-step bidirectional 2-layer LSTM.
// h0=c0=0 => no recurrence, W_hh unused, forget gate dead.
//   gates = inp @ W_ih^T + (b_ih+b_hh); c = sig(i)*tanh(g); h = sig(o)*tanh(c)
// Two GEMMs: (8192 x 3072 x 512) and (8192 x 3072 x 1024); N = 2 dirs x {i,g,o} x 512.
//
// Round-2 changes vs round-1 (which produced NaN):
//  * staging: global_load_lds replaced by uint4 load -> ds_write_b128 (m92/m93 proven path)
//  * runtime dtype detector (bf16 vs f32 inputs) feeding all pack/convert/output kernels
//  * emb gather hoisted out of GEMM into canonical bf16 buffer e0
//
// ws layout (bytes), all 16B-aligned:
//   flag  @ 0
//   bc0   @ 1024        12,288  (3072 f32 combined bias, layer 0)
//   bc1   @ 16384       12,288
//   Wp0   @ 32768       3,145,728   (3072x512  bf16, B^T row-major)
//   Wp1   @ 4194304     6,291,456   (3072x1024 bf16)
//   e0    @ 10485760    8,388,608   (8192x512 bf16 gathered embeddings)
//   inp1  @ 18874368    16,777,216  (8192x1024 bf16)
//   gates @ 35651584    50,331,648  (8192x3072 bf16, reused by both layers)
//   total ~86 MB

using bf16x8 = __attribute__((ext_vector_type(8))) short;
using f32x4  = __attribute__((ext_vector_type(4))) float;

__device__ __forceinline__ float sigf(float x) { return 1.0f / (1.0f + expf(-x)); }
__device__ __forceinline__ unsigned short f2bf(float f)
{
    __hip_bfloat16 h = __float2bfloat16(f);
    return *(unsigned short*)&h;
}

// ---- dtype detector: are the float tensors bf16 (flag=1) or f32 (flag=0)? ----
// Low 16 bits of each u32: for bf16 data it's a real value (exponent in sane range);
// for f32 data it's mantissa junk (exponent ~uniform, ~25% in range).
__global__ void detect(const unsigned int* __restrict__ emb, int* __restrict__ flag)
{
    int ok = 0;
    for (int i = threadIdx.x; i < 256; i += 64) {
        unsigned lo = emb[i] & 0xFFFFu;
        int e = (lo >> 7) & 0xFF;
        if ((e >= 96 && e < 160) || lo == 0) ok++;
    }
#pragma unroll
    for (int off = 32; off; off >>= 1) ok += __shfl_down(ok, off);
    if (threadIdx.x == 0) *flag = (ok >= 192) ? 1 : 0;
}

// ---- gather embeddings into canonical bf16 e0 (8192 x 512) ----
__global__ void gather_convert(const int* __restrict__ x, const void* __restrict__ emb,
                               uint4* __restrict__ e0, const int* __restrict__ flag)
{
    int idx = blockIdx.x * 256 + threadIdx.x;   // one 8-elem chunk each; 8192*64 total
    int m = idx >> 6, r = idx & 63;
    long srow = x[m];
    uint4 v;
    if (*flag) {
        v = ((const uint4*)emb)[srow * 64 + r];
    } else {
        const float4* ef = (const float4*)emb;
        float4 a = ef[srow * 128 + r * 2], b = ef[srow * 128 + r * 2 + 1];
        unsigned short h[8] = { f2bf(a.x), f2bf(a.y), f2bf(a.z), f2bf(a.w),
                                f2bf(b.x), f2bf(b.y), f2bf(b.z), f2bf(b.w) };
        v = *(uint4*)h;
    }
    e0[idx] = v;
}

// ---- pack W_ih rows {i,g,o} x {fwd,bwd} into B^T (3072 x K) canonical bf16 ----
__global__ void pack_w(const void* __restrict__ src, uint4* __restrict__ dst,
                       int k8shift, const int* __restrict__ flag)
{
    int idx = blockIdx.x * 256 + threadIdx.x;   // one 8-elem chunk per thread
    int n = idx >> k8shift;                     // packed row 0..3071
    int r = idx & ((1 << k8shift) - 1);
    int chunk = n >> 9;                         // 0..5
    int dir = (chunk >= 3) ? 1 : 0;
    int gate = chunk - dir * 3;                 // 0:i 1:g 2:o
    int sg = (gate == 0) ? 0 : (gate + 1);      // source gate block {0,2,3} of {i,f,g,o}
    long srcrow = dir * 2048 + sg * 512 + (n & 511);
    long c8 = (srcrow << k8shift) + r;          // 8-element chunk index in source
    if (*flag) {
        dst[idx] = ((const uint4*)src)[c8];
    } else {
        const float4* sf = (const float4*)src;
        float4 a = sf[c8 * 2], b = sf[c8 * 2 + 1];
        unsigned short h[8] = { f2bf(a.x), f2bf(a.y), f2bf(a.z), f2bf(a.w),
                                f2bf(b.x), f2bf(b.y), f2bf(b.z), f2bf(b.w) };
        dst[idx] = *(uint4*)h;
    }
}

__global__ void pack_bias(const void* __restrict__ bi, const void* __restrict__ bh,
                          float* __restrict__ bc, const int* __restrict__ flag)
{
    int n = blockIdx.x * 256 + threadIdx.x;     // 0..3071
    int chunk = n >> 9;
    int dir = (chunk >= 3) ? 1 : 0;
    int gate = chunk - dir * 3;
    int sg = (gate == 0) ? 0 : (gate + 1);
    int s = dir * 2048 + sg * 512 + (n & 511);
    float vi, vh;
    if (*flag) {
        vi = __bfloat162float(((const __hip_bfloat16*)bi)[s]);
        vh = __bfloat162float(((const __hip_bfloat16*)bh)[s]);
    } else {
        vi = ((const float*)bi)[s];
        vh = ((const float*)bh)[s];
    }
    bc[n] = vi + vh;
}

// ---- GEMM: gates(M x 3072) = A(M x K) * Bp(3072 x K)^T, bf16 in/out, f32 acc ----
// 128x128 tile, BK=32, 256 thr = 4 waves, each wave 4x4 of 16x16x32 MFMA.
// Staging: uint4 global load -> register -> ds_write_b128 (m93 pattern).
__global__ __launch_bounds__(256)
void gemm_gates(const unsigned short* __restrict__ A,
                const unsigned short* __restrict__ Bp,
                __hip_bfloat16* __restrict__ gates,
                int K)
{
    constexpr int BM = 128, BK = 32, NCOL = 3072;
    __shared__ __align__(16) unsigned short As[BM * BK];
    __shared__ __align__(16) unsigned short Bs[BM * BK];

    const int tid = threadIdx.x;
    const int bm = blockIdx.x;
    const int bn = blockIdx.y;
    const int K8 = K >> 3;

    // 512 16B chunks per tile; thread owns chunks tid and tid+256.
    // chunk ci -> tile row ci>>2, k-offset (ci&3)*8.
    const int ci0 = tid, ci1 = tid + 256;
    const int ar0 = ci0 >> 2, ar1 = ci1 >> 2;
    const uint4* a4 = (const uint4*)A;
    const uint4* b4 = (const uint4*)Bp;
    const long aBase0 = (long)(bm * BM + ar0) * K8 + (ci0 & 3);
    const long aBase1 = (long)(bm * BM + ar1) * K8 + (ci1 & 3);
    const long bBase0 = (long)(bn * BM + ar0) * K8 + (ci0 & 3);
    const long bBase1 = (long)(bn * BM + ar1) * K8 + (ci1 & 3);

    const int wave = tid >> 6, lane = tid & 63;
    const int wr = (wave >> 1) << 6;            // wave row offset in tile
    const int wc = (wave & 1) << 6;             // wave col offset
    const int lr = lane & 15, q = lane >> 4;

    f32x4 acc[4][4] = {};

    for (int k0 = 0; k0 < K; k0 += BK) {
        const int k8 = k0 >> 3;
        uint4 va0 = a4[aBase0 + k8];
        uint4 va1 = a4[aBase1 + k8];
        uint4 vb0 = b4[bBase0 + k8];
        uint4 vb1 = b4[bBase1 + k8];

        __syncthreads();                        // previous iter's LDS reads done
        ((uint4*)As)[ci0] = va0;
        ((uint4*)As)[ci1] = va1;
        ((uint4*)Bs)[ci0] = vb0;
        ((uint4*)Bs)[ci1] = vb1;
        __syncthreads();                        // staging visible

        bf16x8 af[4], bf[4];
#pragma unroll
        for (int i = 0; i < 4; ++i)
            af[i] = *(const bf16x8*)&As[(wr + i * 16 + lr) * BK + q * 8];
#pragma unroll
        for (int j = 0; j < 4; ++j)
            bf[j] = *(const bf16x8*)&Bs[(wc + j * 16 + lr) * BK + q * 8];
#pragma unroll
        for (int i = 0; i < 4; ++i)
#pragma unroll
            for (int j = 0; j < 4; ++j)
                acc[i][j] = __builtin_amdgcn_mfma_f32_16x16x32_bf16(af[i], bf[j], acc[i][j], 0, 0, 0);
    }

    // D layout: col = lane&15, row = (lane>>4)*4 + reg (m89/m91-verified)
#pragma unroll
    for (int i = 0; i < 4; ++i) {
        long row = (long)bm * BM + wr + i * 16 + q * 4;
#pragma unroll
        for (int j = 0; j < 4; ++j) {
            int col = bn * BM + wc + j * 16 + lr;
#pragma unroll
            for (int r = 0; r < 4; ++r)
                gates[(row + r) * NCOL + col] = __float2bfloat16(acc[i][j][r]);
        }
    }
}

// ---- activation epilogue: one thread per (m,h), both directions ----
// d_out flat: h_last(2,32,512) @0 | c_last(2,32,512) @32768 | enc(B,T,2,H) @65536
template <int LAYER>
__global__ void epilogue(const __hip_bfloat16* __restrict__ g,
                         const float* __restrict__ bc,
                         unsigned short* __restrict__ inp1,
                         void* __restrict__ outv,
                         const int* __restrict__ flag)
{
    int gid = blockIdx.x * 256 + threadIdx.x;   // 0 .. 8192*512-1
    int m = gid >> 9, h = gid & 511;
    long base = (long)m * 3072;
    float z[6];
#pragma unroll
    for (int d = 0; d < 2; ++d)
#pragma unroll
        for (int t = 0; t < 3; ++t) {
            int n = d * 1536 + t * 512 + h;
            z[d * 3 + t] = __bfloat162float(g[base + n]) + bc[n];
        }
    float c0 = sigf(z[0]) * tanhf(z[1]);        // forward dir
    float h0 = sigf(z[2]) * tanhf(c0);
    float c1 = sigf(z[3]) * tanhf(z[4]);        // backward dir
    float h1 = sigf(z[5]) * tanhf(c1);

    if constexpr (LAYER == 0) {
        inp1[(long)m * 1024 + h]       = f2bf(h0);
        inp1[(long)m * 1024 + 512 + h] = f2bf(h1);
    }

    const bool isbf = (*flag != 0);             // uniform branch
    auto store = [&](long i, float v) {
        if (isbf) ((__hip_bfloat16*)outv)[i] = __float2bfloat16(v);
        else      ((float*)outv)[i] = v;
    };
    store(65536 + (long)m * 1024 + LAYER * 512 + h, h0 + h1);   // encoder_out
    if ((m & 255) == 255) {                     // t == T-1
        int b = m >> 8;
        store(LAYER * 16384 + b * 512 + h, h0);                 // h_last (fwd)
        store(32768 + LAYER * 16384 + b * 512 + h, c0);         // c_last (fwd)
    }
}

extern "C" void kernel_launch(void* const* d_in, const int* in_sizes, int n_in,
                              void* d_out, int out_size, void* d_ws, size_t ws_size,
                              hipStream_t stream)
{
    const int* x      = (const int*)d_in[0];
    const void* emb   = d_in[1];
    const void* Wih0  = d_in[2];
    const void* bih0  = d_in[4];
    const void* bhh0  = d_in[5];
    const void* Wih1  = d_in[6];
    const void* bih1  = d_in[8];
    const void* bhh1  = d_in[9];

    char* ws = (char*)d_ws;
    int*   flag           = (int*)(ws);
    float* bc0            = (float*)(ws + 1024);
    float* bc1            = (float*)(ws + 16384);
    unsigned short* Wp0   = (unsigned short*)(ws + 32768);
    unsigned short* Wp1   = (unsigned short*)(ws + 4194304);
    unsigned short* e0    = (unsigned short*)(ws + 10485760);
    unsigned short* inp1  = (unsigned short*)(ws + 18874368);
    __hip_bfloat16* gates = (__hip_bfloat16*)(ws + 35651584);

    detect<<<1, 64, 0, stream>>>((const unsigned int*)emb, flag);
    gather_convert<<<2048, 256, 0, stream>>>(x, emb, (uint4*)e0, flag);
    pack_w<<<768, 256, 0, stream>>>(Wih0, (uint4*)Wp0, 6, flag);    // K=512
    pack_w<<<1536, 256, 0, stream>>>(Wih1, (uint4*)Wp1, 7, flag);   // K=1024
    pack_bias<<<12, 256, 0, stream>>>(bih0, bhh0, bc0, flag);
    pack_bias<<<12, 256, 0, stream>>>(bih1, bhh1, bc1, flag);

    gemm_gates<<<dim3(64, 24), 256, 0, stream>>>(e0, Wp0, gates, 512);
    epilogue<0><<<16384, 256, 0, stream>>>(gates, bc0, inp1, d_out, flag);

    gemm_gates<<<dim3(64, 24), 256, 0, stream>>>(inp1, Wp1, gates, 1024);
    epilogue<1><<<16384, 256, 0, stream>>>(gates, bc1, nullptr, d_out, flag);
}